// Round 6
// baseline (2268.042 us; speedup 1.0000x reference)
//
#include <hip/hip_runtime.h>
#include <math.h>

#define BN_EPS 1e-5f

// ---------------------------------------------------------------------------
// Weight transpose: w[co][ci][kh][kw] -> wt[ci][kpos][co] (co fastest) so
// lane=co weight loads are coalesced 256B dword loads.
// ---------------------------------------------------------------------------
__global__ void wtrans_kernel(const float* __restrict__ w, float* __restrict__ wt) {
    int i = blockIdx.x * 256 + threadIdx.x;
    if (i >= 128 * 128 * 9) return;
    int co = i / 1152;
    int rem = i - co * 1152;
    int ci = rem / 9;
    int kpos = rem - ci * 9;
    wt[ci * 1152 + kpos * 128 + co] = w[i];
}

// ---------------------------------------------------------------------------
// Register-only AdderNet conv helpers.
// ---------------------------------------------------------------------------
__device__ __forceinline__ void load_row(float (&R)[18], const float* rp,
                                         int c0, int colhalf, bool valid) {
    if (valid) {
        float4 q0 = *(const float4*)(rp + c0);
        float4 q1 = *(const float4*)(rp + c0 + 4);
        float4 q2 = *(const float4*)(rp + c0 + 8);
        float4 q3 = *(const float4*)(rp + c0 + 12);
        R[1] = q0.x;  R[2] = q0.y;  R[3] = q0.z;  R[4] = q0.w;
        R[5] = q1.x;  R[6] = q1.y;  R[7] = q1.z;  R[8] = q1.w;
        R[9] = q2.x;  R[10] = q2.y; R[11] = q2.z; R[12] = q2.w;
        R[13] = q3.x; R[14] = q3.y; R[15] = q3.z; R[16] = q3.w;
        R[0]  = colhalf ? rp[c0 - 1] : 0.f;   // left halo (col -1 is zero-pad)
        R[17] = colhalf ? 0.f : rp[c0 + 16];  // right halo (col 32 is zero-pad)
    } else {
#pragma unroll
        for (int i = 0; i < 18; ++i) R[i] = 0.f;
    }
}

__device__ __forceinline__ void load_w(float (&W)[9], const float* wb) {
#pragma unroll
    for (int k = 0; k < 9; ++k) W[k] = wb[k * 128];
}

__device__ __forceinline__ void kh_acc(float (&acc)[16], const float (&R)[18],
                                       float w0, float w1, float w2) {
#pragma unroll
    for (int j = 0; j < 16; ++j)
        acc[j] += fabsf(R[j] - w0) + fabsf(R[j + 1] - w1) + fabsf(R[j + 2] - w2);
}

// ---------------------------------------------------------------------------
// AdderNet conv (3x3, pad 1), PARTIAL over half the ci range. Register-only:
// no LDS, no barriers, no SMEM in the hot loop.
// Grid: (32 rows, 16 n, 2 ci-halves) = 1024 blocks -> 4/CU -> 16 waves/CU.
// Block: 256 thr = 4 waves = (2 col-halves) x (2 co-halves). lane = co.
// Wave: one row x 16 px x 64 co; acc[16]/lane. Weights per-lane VGPR (9
// coalesced dword loads/plane, 2-plane ping-pong). x rows: wave-uniform
// float4 loads, rowbuf reloaded for p+1 right after consumption (stagger).
// Output: positive partial sums, co-fastest layout [n][row][px][co], coalesced.
// ---------------------------------------------------------------------------
__global__ __launch_bounds__(256, 4) void adder_conv_part(
    const float* __restrict__ src,   // [16,128,32,32] standard
    const float* __restrict__ wt,    // [ci][9][co]
    float* __restrict__ dst0, float* __restrict__ dst1) {
    const int t = threadIdx.x;
    const int lane = t & 63;
    const int wid = t >> 6;
    const int colhalf = wid & 1;
    const int cohalf = wid >> 1;
    const int row = blockIdx.x;
    const int n = blockIdx.y;
    const int half = blockIdx.z;
    const int c0 = colhalf << 4;
    const int co = (cohalf << 6) + lane;

    const float* sbase = src + ((size_t)n * 128 + half * 64) * 1024;
    const float* wbase = wt + (size_t)half * 64 * 1152 + co;

    const bool vA = row > 0, vC = row < 31;
    const int grA = (row - 1) * 32, grB = row * 32, grC = (row + 1) * 32;

    float acc[16];
#pragma unroll
    for (int j = 0; j < 16; ++j) acc[j] = 0.f;

    float A[18], B[18], C[18], wv[9], wn[9];
    load_w(wv, wbase);
    load_w(wn, wbase + 1152);
    load_row(A, sbase + grA, c0, colhalf, vA);
    load_row(B, sbase + grB, c0, colhalf, true);
    load_row(C, sbase + grC, c0, colhalf, vC);

#pragma unroll 1
    for (int p = 0; p < 64; p += 2) {
        const bool m2 = (p + 2) < 64, m3 = (p + 3) < 64;
        // even plane p (weights wv); reload each rowbuf for p+1 after use
        kh_acc(acc, A, wv[0], wv[1], wv[2]);
        load_row(A, sbase + (p + 1) * 1024 + grA, c0, colhalf, vA);
        kh_acc(acc, B, wv[3], wv[4], wv[5]);
        load_row(B, sbase + (p + 1) * 1024 + grB, c0, colhalf, true);
        kh_acc(acc, C, wv[6], wv[7], wv[8]);
        load_row(C, sbase + (p + 1) * 1024 + grC, c0, colhalf, vC);
        if (m2) load_w(wv, wbase + (p + 2) * 1152);
        // odd plane p+1 (weights wn)
        kh_acc(acc, A, wn[0], wn[1], wn[2]);
        load_row(A, sbase + (p + 2) * 1024 + grA, c0, colhalf, vA && m2);
        kh_acc(acc, B, wn[3], wn[4], wn[5]);
        load_row(B, sbase + (p + 2) * 1024 + grB, c0, colhalf, m2);
        kh_acc(acc, C, wn[6], wn[7], wn[8]);
        load_row(C, sbase + (p + 2) * 1024 + grC, c0, colhalf, vC && m2);
        if (m3) load_w(wn, wbase + (p + 3) * 1152);
    }

    // Epilogue: coalesced stores, co-fastest partial layout.
    float* dst = half ? dst1 : dst0;
    float* dp = dst + (((size_t)n * 32 + row) * 32 + c0) * 128 + co;
#pragma unroll
    for (int j = 0; j < 16; ++j) dp[j * 128] = acc[j];
}

// ---------------------------------------------------------------------------
// Combine + transpose: partials [n][row][px][co] -> out [n][co][row][px].
// out = BN(-(pA+pB)) (+ReLU). Block per (row, n); LDS 32x129 tile.
// ---------------------------------------------------------------------------
template <bool RELU>
__global__ void combine_bn_t(const float* __restrict__ pA, const float* __restrict__ pB,
                             const float* __restrict__ gamma, const float* __restrict__ beta,
                             const float* __restrict__ mean, const float* __restrict__ var,
                             float* __restrict__ out) {
    const int t = threadIdx.x;
    const int row = blockIdx.x;   // 0..31
    const int n = blockIdx.y;     // 0..15
    __shared__ float tile[32 * 129];
    const size_t base = (((size_t)n * 32 + row) * 32) * 128;  // + px*128 + co

    const int co = t & 127, th = t >> 7;
    const float iv = gamma[co] * rsqrtf(var[co] + BN_EPS);
    const float bb = beta[co] - mean[co] * iv;
#pragma unroll
    for (int e = 0; e < 16; ++e) {
        const int px = e * 2 + th;
        const size_t idx = base + px * 128 + co;
        float z = bb - (pA[idx] + pB[idx]) * iv;
        if (RELU) z = fmaxf(z, 0.f);
        tile[px * 129 + co] = z;
    }
    __syncthreads();
#pragma unroll
    for (int e = 0; e < 4; ++e) {
        const int qidx = e * 256 + t;        // 0..1023 = 128co x 8quads
        const int oco = qidx >> 3, q = qidx & 7;
        float4 v;
        v.x = tile[(4 * q + 0) * 129 + oco];
        v.y = tile[(4 * q + 1) * 129 + oco];
        v.z = tile[(4 * q + 2) * 129 + oco];
        v.w = tile[(4 * q + 3) * 129 + oco];
        *(float4*)&out[(((size_t)n * 128 + oco) * 32 + row) * 32 + 4 * q] = v;
    }
}

// ---------------------------------------------------------------------------
// Per-(n,c) spatial mean of z (standard layout): [16,128,32,32] -> [16,128]
// ---------------------------------------------------------------------------
__global__ void mean_kernel(const float* __restrict__ z, float* __restrict__ means) {
    const int b = blockIdx.x;  // n*128 + c
    const float4 v = ((const float4*)(z + (size_t)b * 1024))[threadIdx.x];
    float sum = v.x + v.y + v.z + v.w;
#pragma unroll
    for (int o = 32; o > 0; o >>= 1) sum += __shfl_down(sum, o);
    __shared__ float ws_[4];
    if ((threadIdx.x & 63) == 0) ws_[threadIdx.x >> 6] = sum;
    __syncthreads();
    if (threadIdx.x == 0)
        means[b] = (ws_[0] + ws_[1] + ws_[2] + ws_[3]) * (1.f / 1024.f);
}

// ---------------------------------------------------------------------------
// SE gate: s = sigmoid(fc2(relu(fc1(mean)+b1))+b2), per image n.
// ---------------------------------------------------------------------------
__global__ void se_kernel(const float* __restrict__ means,
                          const float* __restrict__ fc1w, const float* __restrict__ fc1b,
                          const float* __restrict__ fc2w, const float* __restrict__ fc2b,
                          float* __restrict__ s) {
    const int n = blockIdx.x;     // 16 blocks, 128 threads
    const int t = threadIdx.x;
    __shared__ float m[128], rr[8];
    m[t] = means[n * 128 + t];
    __syncthreads();
    if (t < 8) {
        float a = fc1b[t];
        for (int c2 = 0; c2 < 128; ++c2) a += fc1w[t * 128 + c2] * m[c2];
        rr[t] = fmaxf(a, 0.f);
    }
    __syncthreads();
    float a = fc2b[t];
#pragma unroll
    for (int j = 0; j < 8; ++j) a += fc2w[t * 8 + j] * rr[j];
    s[n * 128 + t] = 1.f / (1.f + expf(-a));
}

// ---------------------------------------------------------------------------
// Final: out = relu(z * s[n,c] + x), vectorized float4 (standard layouts).
// ---------------------------------------------------------------------------
__global__ void final_kernel(const float* __restrict__ z, const float* __restrict__ x,
                             const float* __restrict__ s, float* __restrict__ out) {
    const int i = blockIdx.x * 256 + threadIdx.x;   // float4 index, 524288 total
    const int plane = i >> 8;                        // 256 float4 per (n,c)
    const float sc = s[plane];
    const float4 zv = ((const float4*)z)[i];
    const float4 xv = ((const float4*)x)[i];
    float4 o;
    o.x = fmaxf(zv.x * sc + xv.x, 0.f);
    o.y = fmaxf(zv.y * sc + xv.y, 0.f);
    o.z = fmaxf(zv.z * sc + xv.z, 0.f);
    o.w = fmaxf(zv.w * sc + xv.w, 0.f);
    ((float4*)out)[i] = o;
}

// ---------------------------------------------------------------------------
extern "C" void kernel_launch(void* const* d_in, const int* in_sizes, int n_in,
                              void* d_out, int out_size, void* d_ws, size_t ws_size,
                              hipStream_t stream) {
    const float* x    = (const float*)d_in[0];
    const float* w1   = (const float*)d_in[1];
    const float* g1   = (const float*)d_in[2];
    const float* b1   = (const float*)d_in[3];
    const float* m1   = (const float*)d_in[4];
    const float* v1   = (const float*)d_in[5];
    const float* w2   = (const float*)d_in[6];
    const float* g2   = (const float*)d_in[7];
    const float* b2   = (const float*)d_in[8];
    const float* m2   = (const float*)d_in[9];
    const float* v2   = (const float*)d_in[10];
    const float* fc1w = (const float*)d_in[11];
    const float* fc1b = (const float*)d_in[12];
    const float* fc2w = (const float*)d_in[13];
    const float* fc2b = (const float*)d_in[14];
    float* out = (float*)d_out;

    float* ws    = (float*)d_ws;
    float* wt1   = ws;                   // 147456
    float* wt2   = wt1 + 147456;         // 147456
    float* pA    = wt2 + 147456;         // 2097152 (split-0 partial, co-fast)
    float* pB    = pA + 2097152;         // 2097152 (split-1 partial, co-fast)
    float* y     = pB + 2097152;         // 2097152 (standard; reused as z)
    float* means = y + 2097152;          // 2048
    float* s     = means + 2048;         // 2048
    float* z     = y;                    // combine2 output reuses y buffer

    wtrans_kernel<<<576, 256, 0, stream>>>(w1, wt1);
    wtrans_kernel<<<576, 256, 0, stream>>>(w2, wt2);

    dim3 cgrid(32, 16, 2);
    dim3 tgrid(32, 16);
    // Conv1 partials -> pA/pB; combine+transpose -> y (standard, +ReLU).
    adder_conv_part<<<cgrid, 256, 0, stream>>>(x, wt1, pA, pB);
    combine_bn_t<true ><<<tgrid, 256, 0, stream>>>(pA, pB, g1, b1, m1, v1, y);
    // Conv2 partials (src = y) -> pA/pB; combine+transpose -> z.
    adder_conv_part<<<cgrid, 256, 0, stream>>>(y, wt2, pA, pB);
    combine_bn_t<false><<<tgrid, 256, 0, stream>>>(pA, pB, g2, b2, m2, v2, z);

    mean_kernel<<<2048, 256, 0, stream>>>(z, means);
    se_kernel<<<16, 128, 0, stream>>>(means, fc1w, fc1b, fc2w, fc2b, s);
    final_kernel<<<2048, 256, 0, stream>>>(z, x, s, out);
}

// Round 7
// 851.125 us; speedup vs baseline: 2.6648x; 2.6648x over previous
//
#include <hip/hip_runtime.h>
#include <math.h>

#define BN_EPS 1e-5f

// ---------------------------------------------------------------------------
// Weight transpose: w[co][ci][kh][kw] -> wt[ci][kpos][co] (co fastest) so
// lane=co weight loads are coalesced 256B dword loads.
// ---------------------------------------------------------------------------
__global__ void wtrans_kernel(const float* __restrict__ w, float* __restrict__ wt) {
    int i = blockIdx.x * 256 + threadIdx.x;
    if (i >= 128 * 128 * 9) return;
    int co = i / 1152;
    int rem = i - co * 1152;
    int ci = rem / 9;
    int kpos = rem - ci * 9;
    wt[ci * 1152 + kpos * 128 + co] = w[i];
}

// ---------------------------------------------------------------------------
// Register-only AdderNet conv helpers.
// ---------------------------------------------------------------------------
__device__ __forceinline__ void load_row(float (&R)[18], const float* rp,
                                         int c0, int colhalf, bool valid) {
    if (valid) {
        float4 q0 = *(const float4*)(rp + c0);
        float4 q1 = *(const float4*)(rp + c0 + 4);
        float4 q2 = *(const float4*)(rp + c0 + 8);
        float4 q3 = *(const float4*)(rp + c0 + 12);
        R[1] = q0.x;  R[2] = q0.y;  R[3] = q0.z;  R[4] = q0.w;
        R[5] = q1.x;  R[6] = q1.y;  R[7] = q1.z;  R[8] = q1.w;
        R[9] = q2.x;  R[10] = q2.y; R[11] = q2.z; R[12] = q2.w;
        R[13] = q3.x; R[14] = q3.y; R[15] = q3.z; R[16] = q3.w;
        R[0]  = colhalf ? rp[c0 - 1] : 0.f;   // left halo (col -1 is zero-pad)
        R[17] = colhalf ? 0.f : rp[c0 + 16];  // right halo (col 32 is zero-pad)
    } else {
#pragma unroll
        for (int i = 0; i < 18; ++i) R[i] = 0.f;
    }
}

__device__ __forceinline__ void load_w(float (&W)[9], const float* wb) {
#pragma unroll
    for (int k = 0; k < 9; ++k) W[k] = wb[k * 128];
}

__device__ __forceinline__ void kh_acc(float (&acc)[16], const float (&R)[18],
                                       float w0, float w1, float w2) {
#pragma unroll
    for (int j = 0; j < 16; ++j)
        acc[j] += fabsf(R[j] - w0) + fabsf(R[j + 1] - w1) + fabsf(R[j + 2] - w2);
}

// ---------------------------------------------------------------------------
// AdderNet conv (3x3, pad 1), PARTIAL over half the ci range. Register-only:
// no LDS, no barriers, no SMEM in the hot loop.
// Grid: (32 rows, 16 n, 2 ci-halves) = 1024 blocks -> 4/CU -> 16 waves/CU.
// Block: 256 thr = 4 waves = (2 col-halves) x (2 co-halves). lane = co.
// Wave: one row x 16 px x 64 co; acc[16]/lane. Weights per-lane VGPR (9
// coalesced dword loads/plane, 2-plane ping-pong). x rows: wave-uniform
// float4 loads, rowbuf reloaded for p+1 right after consumption (stagger).
// NO min-occupancy bound: live state ~105 VGPR; r6's (256,4) forced 64 VGPR
// -> 6 GB/dispatch scratch spill traffic. Natural ~105 VGPR still gives
// 4 waves/SIMD.
// Output: positive partial sums, co-fastest layout [n][row][px][co], coalesced.
// ---------------------------------------------------------------------------
__global__ __launch_bounds__(256) void adder_conv_part(
    const float* __restrict__ src,   // [16,128,32,32] standard
    const float* __restrict__ wt,    // [ci][9][co]
    float* __restrict__ dst0, float* __restrict__ dst1) {
    const int t = threadIdx.x;
    const int lane = t & 63;
    const int wid = t >> 6;
    const int colhalf = wid & 1;
    const int cohalf = wid >> 1;
    const int row = blockIdx.x;
    const int n = blockIdx.y;
    const int half = blockIdx.z;
    const int c0 = colhalf << 4;
    const int co = (cohalf << 6) + lane;

    const float* sbase = src + ((size_t)n * 128 + half * 64) * 1024;
    const float* wbase = wt + (size_t)half * 64 * 1152 + co;

    const bool vA = row > 0, vC = row < 31;
    const int grA = (row - 1) * 32, grB = row * 32, grC = (row + 1) * 32;

    float acc[16];
#pragma unroll
    for (int j = 0; j < 16; ++j) acc[j] = 0.f;

    float A[18], B[18], C[18], wv[9], wn[9];
    load_w(wv, wbase);
    load_w(wn, wbase + 1152);
    load_row(A, sbase + grA, c0, colhalf, vA);
    load_row(B, sbase + grB, c0, colhalf, true);
    load_row(C, sbase + grC, c0, colhalf, vC);

#pragma unroll 1
    for (int p = 0; p < 64; p += 2) {
        const bool m2 = (p + 2) < 64, m3 = (p + 3) < 64;
        // even plane p (weights wv); reload each rowbuf for p+1 after use
        kh_acc(acc, A, wv[0], wv[1], wv[2]);
        load_row(A, sbase + (p + 1) * 1024 + grA, c0, colhalf, vA);
        kh_acc(acc, B, wv[3], wv[4], wv[5]);
        load_row(B, sbase + (p + 1) * 1024 + grB, c0, colhalf, true);
        kh_acc(acc, C, wv[6], wv[7], wv[8]);
        load_row(C, sbase + (p + 1) * 1024 + grC, c0, colhalf, vC);
        if (m2) load_w(wv, wbase + (p + 2) * 1152);
        // odd plane p+1 (weights wn)
        kh_acc(acc, A, wn[0], wn[1], wn[2]);
        load_row(A, sbase + (p + 2) * 1024 + grA, c0, colhalf, vA && m2);
        kh_acc(acc, B, wn[3], wn[4], wn[5]);
        load_row(B, sbase + (p + 2) * 1024 + grB, c0, colhalf, m2);
        kh_acc(acc, C, wn[6], wn[7], wn[8]);
        load_row(C, sbase + (p + 2) * 1024 + grC, c0, colhalf, vC && m2);
        if (m3) load_w(wn, wbase + (p + 3) * 1152);
    }

    // Epilogue: coalesced stores, co-fastest partial layout.
    float* dst = half ? dst1 : dst0;
    float* dp = dst + (((size_t)n * 32 + row) * 32 + c0) * 128 + co;
#pragma unroll
    for (int j = 0; j < 16; ++j) dp[j * 128] = acc[j];
}

// ---------------------------------------------------------------------------
// Combine + transpose: partials [n][row][px][co] -> out [n][co][row][px].
// out = BN(-(pA+pB)) (+ReLU). Block per (row, n); LDS 32x129 tile.
// ---------------------------------------------------------------------------
template <bool RELU>
__global__ void combine_bn_t(const float* __restrict__ pA, const float* __restrict__ pB,
                             const float* __restrict__ gamma, const float* __restrict__ beta,
                             const float* __restrict__ mean, const float* __restrict__ var,
                             float* __restrict__ out) {
    const int t = threadIdx.x;
    const int row = blockIdx.x;   // 0..31
    const int n = blockIdx.y;     // 0..15
    __shared__ float tile[32 * 129];
    const size_t base = (((size_t)n * 32 + row) * 32) * 128;  // + px*128 + co

    const int co = t & 127, th = t >> 7;
    const float iv = gamma[co] * rsqrtf(var[co] + BN_EPS);
    const float bb = beta[co] - mean[co] * iv;
#pragma unroll
    for (int e = 0; e < 16; ++e) {
        const int px = e * 2 + th;
        const size_t idx = base + px * 128 + co;
        float z = bb - (pA[idx] + pB[idx]) * iv;
        if (RELU) z = fmaxf(z, 0.f);
        tile[px * 129 + co] = z;
    }
    __syncthreads();
#pragma unroll
    for (int e = 0; e < 4; ++e) {
        const int qidx = e * 256 + t;        // 0..1023 = 128co x 8quads
        const int oco = qidx >> 3, q = qidx & 7;
        float4 v;
        v.x = tile[(4 * q + 0) * 129 + oco];
        v.y = tile[(4 * q + 1) * 129 + oco];
        v.z = tile[(4 * q + 2) * 129 + oco];
        v.w = tile[(4 * q + 3) * 129 + oco];
        *(float4*)&out[(((size_t)n * 128 + oco) * 32 + row) * 32 + 4 * q] = v;
    }
}

// ---------------------------------------------------------------------------
// Per-(n,c) spatial mean of z (standard layout): [16,128,32,32] -> [16,128]
// ---------------------------------------------------------------------------
__global__ void mean_kernel(const float* __restrict__ z, float* __restrict__ means) {
    const int b = blockIdx.x;  // n*128 + c
    const float4 v = ((const float4*)(z + (size_t)b * 1024))[threadIdx.x];
    float sum = v.x + v.y + v.z + v.w;
#pragma unroll
    for (int o = 32; o > 0; o >>= 1) sum += __shfl_down(sum, o);
    __shared__ float ws_[4];
    if ((threadIdx.x & 63) == 0) ws_[threadIdx.x >> 6] = sum;
    __syncthreads();
    if (threadIdx.x == 0)
        means[b] = (ws_[0] + ws_[1] + ws_[2] + ws_[3]) * (1.f / 1024.f);
}

// ---------------------------------------------------------------------------
// SE gate: s = sigmoid(fc2(relu(fc1(mean)+b1))+b2), per image n.
// ---------------------------------------------------------------------------
__global__ void se_kernel(const float* __restrict__ means,
                          const float* __restrict__ fc1w, const float* __restrict__ fc1b,
                          const float* __restrict__ fc2w, const float* __restrict__ fc2b,
                          float* __restrict__ s) {
    const int n = blockIdx.x;     // 16 blocks, 128 threads
    const int t = threadIdx.x;
    __shared__ float m[128], rr[8];
    m[t] = means[n * 128 + t];
    __syncthreads();
    if (t < 8) {
        float a = fc1b[t];
        for (int c2 = 0; c2 < 128; ++c2) a += fc1w[t * 128 + c2] * m[c2];
        rr[t] = fmaxf(a, 0.f);
    }
    __syncthreads();
    float a = fc2b[t];
#pragma unroll
    for (int j = 0; j < 8; ++j) a += fc2w[t * 8 + j] * rr[j];
    s[n * 128 + t] = 1.f / (1.f + expf(-a));
}

// ---------------------------------------------------------------------------
// Final: out = relu(z * s[n,c] + x), vectorized float4 (standard layouts).
// ---------------------------------------------------------------------------
__global__ void final_kernel(const float* __restrict__ z, const float* __restrict__ x,
                             const float* __restrict__ s, float* __restrict__ out) {
    const int i = blockIdx.x * 256 + threadIdx.x;   // float4 index, 524288 total
    const int plane = i >> 8;                        // 256 float4 per (n,c)
    const float sc = s[plane];
    const float4 zv = ((const float4*)z)[i];
    const float4 xv = ((const float4*)x)[i];
    float4 o;
    o.x = fmaxf(zv.x * sc + xv.x, 0.f);
    o.y = fmaxf(zv.y * sc + xv.y, 0.f);
    o.z = fmaxf(zv.z * sc + xv.z, 0.f);
    o.w = fmaxf(zv.w * sc + xv.w, 0.f);
    ((float4*)out)[i] = o;
}

// ---------------------------------------------------------------------------
extern "C" void kernel_launch(void* const* d_in, const int* in_sizes, int n_in,
                              void* d_out, int out_size, void* d_ws, size_t ws_size,
                              hipStream_t stream) {
    const float* x    = (const float*)d_in[0];
    const float* w1   = (const float*)d_in[1];
    const float* g1   = (const float*)d_in[2];
    const float* b1   = (const float*)d_in[3];
    const float* m1   = (const float*)d_in[4];
    const float* v1   = (const float*)d_in[5];
    const float* w2   = (const float*)d_in[6];
    const float* g2   = (const float*)d_in[7];
    const float* b2   = (const float*)d_in[8];
    const float* m2   = (const float*)d_in[9];
    const float* v2   = (const float*)d_in[10];
    const float* fc1w = (const float*)d_in[11];
    const float* fc1b = (const float*)d_in[12];
    const float* fc2w = (const float*)d_in[13];
    const float* fc2b = (const float*)d_in[14];
    float* out = (float*)d_out;

    float* ws    = (float*)d_ws;
    float* wt1   = ws;                   // 147456
    float* wt2   = wt1 + 147456;         // 147456
    float* pA    = wt2 + 147456;         // 2097152 (split-0 partial, co-fast)
    float* pB    = pA + 2097152;         // 2097152 (split-1 partial, co-fast)
    float* y     = pB + 2097152;         // 2097152 (standard; reused as z)
    float* means = y + 2097152;          // 2048
    float* s     = means + 2048;         // 2048
    float* z     = y;                    // combine2 output reuses y buffer

    wtrans_kernel<<<576, 256, 0, stream>>>(w1, wt1);
    wtrans_kernel<<<576, 256, 0, stream>>>(w2, wt2);

    dim3 cgrid(32, 16, 2);
    dim3 tgrid(32, 16);
    // Conv1 partials -> pA/pB; combine+transpose -> y (standard, +ReLU).
    adder_conv_part<<<cgrid, 256, 0, stream>>>(x, wt1, pA, pB);
    combine_bn_t<true ><<<tgrid, 256, 0, stream>>>(pA, pB, g1, b1, m1, v1, y);
    // Conv2 partials (src = y) -> pA/pB; combine+transpose -> z.
    adder_conv_part<<<cgrid, 256, 0, stream>>>(y, wt2, pA, pB);
    combine_bn_t<false><<<tgrid, 256, 0, stream>>>(pA, pB, g2, b2, m2, v2, z);

    mean_kernel<<<2048, 256, 0, stream>>>(z, means);
    se_kernel<<<16, 128, 0, stream>>>(means, fc1w, fc1b, fc2w, fc2b, s);
    final_kernel<<<2048, 256, 0, stream>>>(z, x, s, out);
}

// Round 9
// 529.856 us; speedup vs baseline: 4.2805x; 1.6063x over previous
//
#include <hip/hip_runtime.h>
#include <math.h>

#define BN_EPS 1e-5f

// ---------------------------------------------------------------------------
// Weight transpose: w[co][ci][kh][kw] -> wt[ci][kpos][co] (co fastest) so
// lane=co weight loads are coalesced 256B dword loads.
// ---------------------------------------------------------------------------
__global__ void wtrans_kernel(const float* __restrict__ w, float* __restrict__ wt) {
    int i = blockIdx.x * 256 + threadIdx.x;
    if (i >= 128 * 128 * 9) return;
    int co = i / 1152;
    int rem = i - co * 1152;
    int ci = rem / 9;
    int kpos = rem - ci * 9;
    wt[ci * 1152 + kpos * 128 + co] = w[i];
}

// ---------------------------------------------------------------------------
// Register-only AdderNet conv helpers.
// ---------------------------------------------------------------------------
__device__ __forceinline__ void load_row(float (&R)[18], const float* rp,
                                         int c0, int colhalf, bool valid) {
    if (valid) {
        float4 q0 = *(const float4*)(rp + c0);
        float4 q1 = *(const float4*)(rp + c0 + 4);
        float4 q2 = *(const float4*)(rp + c0 + 8);
        float4 q3 = *(const float4*)(rp + c0 + 12);
        R[1] = q0.x;  R[2] = q0.y;  R[3] = q0.z;  R[4] = q0.w;
        R[5] = q1.x;  R[6] = q1.y;  R[7] = q1.z;  R[8] = q1.w;
        R[9] = q2.x;  R[10] = q2.y; R[11] = q2.z; R[12] = q2.w;
        R[13] = q3.x; R[14] = q3.y; R[15] = q3.z; R[16] = q3.w;
        R[0]  = colhalf ? rp[c0 - 1] : 0.f;   // left halo (col -1 is zero-pad)
        R[17] = colhalf ? 0.f : rp[c0 + 16];  // right halo (col 32 is zero-pad)
    } else {
#pragma unroll
        for (int i = 0; i < 18; ++i) R[i] = 0.f;
    }
}

__device__ __forceinline__ void load_w(float (&W)[9], const float* wb) {
#pragma unroll
    for (int k = 0; k < 9; ++k) W[k] = wb[k * 128];
}

__device__ __forceinline__ void kh_acc(float (&acc)[16], const float (&R)[18],
                                       float w0, float w1, float w2) {
#pragma unroll
    for (int j = 0; j < 16; ++j)
        acc[j] += fabsf(R[j] - w0) + fabsf(R[j + 1] - w1) + fabsf(R[j + 2] - w2);
}

// ---------------------------------------------------------------------------
// AdderNet conv (3x3, pad 1), PARTIAL over half the ci range. Register-only:
// no LDS, no barriers, no SMEM in the hot loop.
// Grid: 1024 blocks, 1D, XCD-SWIZZLED decode: xcd = bid&7 owns n in
// {2*xcd, 2*xcd+1} -> per-XCD x working set = 1MB (+0.6MB weights) < 4MB L2.
// Block: 256 thr = 4 waves = (2 col-halves) x (2 co-halves). lane = co.
// Wave: one row x 16 px x 64 co; acc[16]/lane. Weights per-lane VGPR (9
// coalesced dword loads/plane, 2-plane ping-pong). x rows: wave-uniform
// float4 loads, rowbuf reloaded for p+1 right after consumption (stagger).
// __launch_bounds__(256,2): empirical cap = 256/N -> 128 VGPR (r7's natural
// 136 fell off the 128 occupancy cliff to 2 waves/SIMD). Live state ~105
// floats fits 128 without spills -> 4 waves/SIMD.
// Output: positive partial sums, co-fastest layout [n][row][px][co], coalesced.
// ---------------------------------------------------------------------------
__global__ __launch_bounds__(256, 2) void adder_conv_part(
    const float* __restrict__ src,   // [16,128,32,32] standard
    const float* __restrict__ wt,    // [ci][9][co]
    float* __restrict__ dst0, float* __restrict__ dst1) {
    const int t = threadIdx.x;
    const int lane = t & 63;
    const int wid = t >> 6;
    const int colhalf = wid & 1;
    const int cohalf = wid >> 1;

    // XCD-aware decode: bid%8 = XCD (observed round-robin dispatch).
    const int bid = blockIdx.x;
    const int xcd = bid & 7;
    const int slot = bid >> 3;            // 0..127
    const int nbit = slot >> 6;           // 0..1
    const int rem = slot & 63;
    const int row = rem & 31;
    const int half = rem >> 5;
    const int n = xcd * 2 + nbit;

    const int c0 = colhalf << 4;
    const int co = (cohalf << 6) + lane;

    const float* sbase = src + ((size_t)n * 128 + half * 64) * 1024;
    const float* wbase = wt + (size_t)half * 64 * 1152 + co;

    const bool vA = row > 0, vC = row < 31;
    const int grA = (row - 1) * 32, grB = row * 32, grC = (row + 1) * 32;

    float acc[16];
#pragma unroll
    for (int j = 0; j < 16; ++j) acc[j] = 0.f;

    float A[18], B[18], C[18], wv[9], wn[9];
    load_w(wv, wbase);
    load_w(wn, wbase + 1152);
    load_row(A, sbase + grA, c0, colhalf, vA);
    load_row(B, sbase + grB, c0, colhalf, true);
    load_row(C, sbase + grC, c0, colhalf, vC);

#pragma unroll 1
    for (int p = 0; p < 64; p += 2) {
        const bool m2 = (p + 2) < 64, m3 = (p + 3) < 64;
        // even plane p (weights wv); reload each rowbuf for p+1 after use
        kh_acc(acc, A, wv[0], wv[1], wv[2]);
        load_row(A, sbase + (p + 1) * 1024 + grA, c0, colhalf, vA);
        kh_acc(acc, B, wv[3], wv[4], wv[5]);
        load_row(B, sbase + (p + 1) * 1024 + grB, c0, colhalf, true);
        kh_acc(acc, C, wv[6], wv[7], wv[8]);
        load_row(C, sbase + (p + 1) * 1024 + grC, c0, colhalf, vC);
        if (m2) load_w(wv, wbase + (p + 2) * 1152);
        // odd plane p+1 (weights wn)
        kh_acc(acc, A, wn[0], wn[1], wn[2]);
        load_row(A, sbase + (p + 2) * 1024 + grA, c0, colhalf, vA && m2);
        kh_acc(acc, B, wn[3], wn[4], wn[5]);
        load_row(B, sbase + (p + 2) * 1024 + grB, c0, colhalf, m2);
        kh_acc(acc, C, wn[6], wn[7], wn[8]);
        load_row(C, sbase + (p + 2) * 1024 + grC, c0, colhalf, vC && m2);
        if (m3) load_w(wn, wbase + (p + 3) * 1152);
    }

    // Epilogue: coalesced stores, co-fastest partial layout.
    float* dst = half ? dst1 : dst0;
    float* dp = dst + (((size_t)n * 32 + row) * 32 + c0) * 128 + co;
#pragma unroll
    for (int j = 0; j < 16; ++j) dp[j * 128] = acc[j];
}

// ---------------------------------------------------------------------------
// Combine + transpose: partials [n][row][px][co] -> out [n][co][row][px].
// out = BN(-(pA+pB)) (+ReLU). Block per (row, n); LDS 32x129 tile.
// ---------------------------------------------------------------------------
template <bool RELU>
__global__ void combine_bn_t(const float* __restrict__ pA, const float* __restrict__ pB,
                             const float* __restrict__ gamma, const float* __restrict__ beta,
                             const float* __restrict__ mean, const float* __restrict__ var,
                             float* __restrict__ out) {
    const int t = threadIdx.x;
    const int row = blockIdx.x;   // 0..31
    const int n = blockIdx.y;     // 0..15
    __shared__ float tile[32 * 129];
    const size_t base = (((size_t)n * 32 + row) * 32) * 128;  // + px*128 + co

    const int co = t & 127, th = t >> 7;
    const float iv = gamma[co] * rsqrtf(var[co] + BN_EPS);
    const float bb = beta[co] - mean[co] * iv;
#pragma unroll
    for (int e = 0; e < 16; ++e) {
        const int px = e * 2 + th;
        const size_t idx = base + px * 128 + co;
        float z = bb - (pA[idx] + pB[idx]) * iv;
        if (RELU) z = fmaxf(z, 0.f);
        tile[px * 129 + co] = z;
    }
    __syncthreads();
#pragma unroll
    for (int e = 0; e < 4; ++e) {
        const int qidx = e * 256 + t;        // 0..1023 = 128co x 8quads
        const int oco = qidx >> 3, q = qidx & 7;
        float4 v;
        v.x = tile[(4 * q + 0) * 129 + oco];
        v.y = tile[(4 * q + 1) * 129 + oco];
        v.z = tile[(4 * q + 2) * 129 + oco];
        v.w = tile[(4 * q + 3) * 129 + oco];
        *(float4*)&out[(((size_t)n * 128 + oco) * 32 + row) * 32 + 4 * q] = v;
    }
}

// ---------------------------------------------------------------------------
// Per-(n,c) spatial mean of z (standard layout): [16,128,32,32] -> [16,128]
// ---------------------------------------------------------------------------
__global__ void mean_kernel(const float* __restrict__ z, float* __restrict__ means) {
    const int b = blockIdx.x;  // n*128 + c
    const float4 v = ((const float4*)(z + (size_t)b * 1024))[threadIdx.x];
    float sum = v.x + v.y + v.z + v.w;
#pragma unroll
    for (int o = 32; o > 0; o >>= 1) sum += __shfl_down(sum, o);
    __shared__ float ws_[4];
    if ((threadIdx.x & 63) == 0) ws_[threadIdx.x >> 6] = sum;
    __syncthreads();
    if (threadIdx.x == 0)
        means[b] = (ws_[0] + ws_[1] + ws_[2] + ws_[3]) * (1.f / 1024.f);
}

// ---------------------------------------------------------------------------
// SE gate: s = sigmoid(fc2(relu(fc1(mean)+b1))+b2), per image n.
// ---------------------------------------------------------------------------
__global__ void se_kernel(const float* __restrict__ means,
                          const float* __restrict__ fc1w, const float* __restrict__ fc1b,
                          const float* __restrict__ fc2w, const float* __restrict__ fc2b,
                          float* __restrict__ s) {
    const int n = blockIdx.x;     // 16 blocks, 128 threads
    const int t = threadIdx.x;
    __shared__ float m[128], rr[8];
    m[t] = means[n * 128 + t];
    __syncthreads();
    if (t < 8) {
        float a = fc1b[t];
        for (int c2 = 0; c2 < 128; ++c2) a += fc1w[t * 128 + c2] * m[c2];
        rr[t] = fmaxf(a, 0.f);
    }
    __syncthreads();
    float a = fc2b[t];
#pragma unroll
    for (int j = 0; j < 8; ++j) a += fc2w[t * 8 + j] * rr[j];
    s[n * 128 + t] = 1.f / (1.f + expf(-a));
}

// ---------------------------------------------------------------------------
// Final: out = relu(z * s[n,c] + x), vectorized float4 (standard layouts).
// ---------------------------------------------------------------------------
__global__ void final_kernel(const float* __restrict__ z, const float* __restrict__ x,
                             const float* __restrict__ s, float* __restrict__ out) {
    const int i = blockIdx.x * 256 + threadIdx.x;   // float4 index, 524288 total
    const int plane = i >> 8;                        // 256 float4 per (n,c)
    const float sc = s[plane];
    const float4 zv = ((const float4*)z)[i];
    const float4 xv = ((const float4*)x)[i];
    float4 o;
    o.x = fmaxf(zv.x * sc + xv.x, 0.f);
    o.y = fmaxf(zv.y * sc + xv.y, 0.f);
    o.z = fmaxf(zv.z * sc + xv.z, 0.f);
    o.w = fmaxf(zv.w * sc + xv.w, 0.f);
    ((float4*)out)[i] = o;
}

// ---------------------------------------------------------------------------
extern "C" void kernel_launch(void* const* d_in, const int* in_sizes, int n_in,
                              void* d_out, int out_size, void* d_ws, size_t ws_size,
                              hipStream_t stream) {
    const float* x    = (const float*)d_in[0];
    const float* w1   = (const float*)d_in[1];
    const float* g1   = (const float*)d_in[2];
    const float* b1   = (const float*)d_in[3];
    const float* m1   = (const float*)d_in[4];
    const float* v1   = (const float*)d_in[5];
    const float* w2   = (const float*)d_in[6];
    const float* g2   = (const float*)d_in[7];
    const float* b2   = (const float*)d_in[8];
    const float* m2   = (const float*)d_in[9];
    const float* v2   = (const float*)d_in[10];
    const float* fc1w = (const float*)d_in[11];
    const float* fc1b = (const float*)d_in[12];
    const float* fc2w = (const float*)d_in[13];
    const float* fc2b = (const float*)d_in[14];
    float* out = (float*)d_out;

    float* ws    = (float*)d_ws;
    float* wt1   = ws;                   // 147456
    float* wt2   = wt1 + 147456;         // 147456
    float* pA    = wt2 + 147456;         // 2097152 (split-0 partial, co-fast)
    float* pB    = pA + 2097152;         // 2097152 (split-1 partial, co-fast)
    float* y     = pB + 2097152;         // 2097152 (standard; reused as z)
    float* means = y + 2097152;          // 2048
    float* s     = means + 2048;         // 2048
    float* z     = y;                    // combine2 output reuses y buffer

    wtrans_kernel<<<576, 256, 0, stream>>>(w1, wt1);
    wtrans_kernel<<<576, 256, 0, stream>>>(w2, wt2);

    dim3 tgrid(32, 16);
    // Conv1 partials -> pA/pB; combine+transpose -> y (standard, +ReLU).
    adder_conv_part<<<1024, 256, 0, stream>>>(x, wt1, pA, pB);
    combine_bn_t<true ><<<tgrid, 256, 0, stream>>>(pA, pB, g1, b1, m1, v1, y);
    // Conv2 partials (src = y) -> pA/pB; combine+transpose -> z.
    adder_conv_part<<<1024, 256, 0, stream>>>(y, wt2, pA, pB);
    combine_bn_t<false><<<tgrid, 256, 0, stream>>>(pA, pB, g2, b2, m2, v2, z);

    mean_kernel<<<2048, 256, 0, stream>>>(z, means);
    se_kernel<<<16, 128, 0, stream>>>(means, fc1w, fc1b, fc2w, fc2b, s);
    final_kernel<<<2048, 256, 0, stream>>>(z, x, s, out);
}

// Round 10
// 401.328 us; speedup vs baseline: 5.6513x; 1.3203x over previous
//
#include <hip/hip_runtime.h>
#include <math.h>

#define BN_EPS 1e-5f

// ---------------------------------------------------------------------------
// Weight transpose: w[co][ci][kh][kw] -> wt[ci][kpos][co] (co fastest) so
// lane=co weight loads are coalesced 256B dword loads.
// ---------------------------------------------------------------------------
__global__ void wtrans_kernel(const float* __restrict__ w, float* __restrict__ wt) {
    int i = blockIdx.x * 256 + threadIdx.x;
    if (i >= 128 * 128 * 9) return;
    int co = i / 1152;
    int rem = i - co * 1152;
    int ci = rem / 9;
    int kpos = rem - ci * 9;
    wt[ci * 1152 + kpos * 128 + co] = w[i];
}

// ---------------------------------------------------------------------------
// Pad x: [16,128,32,32] -> [16,128,34,36] with zero halo (rows/cols -1..32;
// cols 34,35 are alignment slack, never read).
// ---------------------------------------------------------------------------
__global__ void pad_x_kernel(const float* __restrict__ x, float* __restrict__ xp) {
    const int plane = blockIdx.x;            // n*128 + ci
    const float* sp = x + (size_t)plane * 1024;
    float* dp = xp + (size_t)plane * 1224;
    for (int e = threadIdx.x; e < 1224; e += 256) {
        const int pr = e / 36, pc = e - pr * 36;
        const int r = pr - 1, c = pc - 1;
        float v = 0.f;
        if ((unsigned)r < 32u && (unsigned)c < 32u) v = sp[r * 32 + c];
        dp[e] = v;
    }
}

// Zero only the border cells of a padded buffer (interior written by combine).
__global__ void zero_borders_kernel(float* __restrict__ yp) {
    const int plane = blockIdx.x;            // 2048
    float* dp = yp + (size_t)plane * 1224;
    const int t = threadIdx.x;               // 256 threads, 136 used
    if (t < 36) dp[t] = 0.f;                            // padded row 0
    else if (t < 72) dp[33 * 36 + (t - 36)] = 0.f;      // padded row 33
    else if (t < 104) dp[(t - 71) * 36] = 0.f;          // rows 1..32, col 0
    else if (t < 136) dp[(t - 103) * 36 + 33] = 0.f;    // rows 1..32, col 33
}

// ---------------------------------------------------------------------------
// Register-only AdderNet conv helpers (padded source -> unconditional loads).
// ---------------------------------------------------------------------------
__device__ __forceinline__ void load_rowP(float (&R)[18], const float* rp) {
    float4 q0 = *(const float4*)(rp);
    float4 q1 = *(const float4*)(rp + 4);
    float4 q2 = *(const float4*)(rp + 8);
    float4 q3 = *(const float4*)(rp + 12);
    float2 q4 = *(const float2*)(rp + 16);
    R[0] = q0.x;  R[1] = q0.y;  R[2] = q0.z;  R[3] = q0.w;
    R[4] = q1.x;  R[5] = q1.y;  R[6] = q1.z;  R[7] = q1.w;
    R[8] = q2.x;  R[9] = q2.y;  R[10] = q2.z; R[11] = q2.w;
    R[12] = q3.x; R[13] = q3.y; R[14] = q3.z; R[15] = q3.w;
    R[16] = q4.x; R[17] = q4.y;
}

__device__ __forceinline__ void kh_acc(float (&acc)[16], const float (&R)[18],
                                       float w0, float w1, float w2) {
#pragma unroll
    for (int j = 0; j < 16; ++j)
        acc[j] += fabsf(R[j] - w0) + fabsf(R[j + 1] - w1) + fabsf(R[j + 2] - w2);
}

// ---------------------------------------------------------------------------
// AdderNet conv (3x3, pad 1), PARTIAL over half the ci range. Register-only:
// no LDS, no barriers, no SMEM, NO conditionals in the hot loop.
// Grid: 1024 blocks 1D, XCD swizzle (bid&7 -> n pair) for L2 residency.
// Block: 256 thr = 4 waves = (2 col-halves) x (2 co-halves). lane = co.
// Wave: one row x 16 px x 64 co; acc[16]/lane.
// Per plane: 3x {kh_acc(96 VALU); reload rowbuf for p+1; reload 3 weights
// for p+1} -> every load has ~384 cyc of VALU cover before its use.
// Live state ~79 floats + addressing -> fits the 128-VGPR cap SPILL-FREE
// (r9: natural 136 under cap 128 spilled ~8 regs -> 19MB scratch writes and
// vmcnt(0) drains every plane; that was the 290us limiter).
// Output: positive partial sums, co-fastest layout [n][row][px][co].
// ---------------------------------------------------------------------------
__global__ __launch_bounds__(256, 2) void adder_conv_part(
    const float* __restrict__ src,   // PADDED [16,128,34,36]
    const float* __restrict__ wt,    // [ci][9][co]
    float* __restrict__ dst0, float* __restrict__ dst1) {
    const int t = threadIdx.x;
    const int lane = t & 63;
    const int wid = t >> 6;
    const int colhalf = wid & 1;
    const int cohalf = wid >> 1;

    // XCD-aware decode: bid%8 = XCD (round-robin dispatch).
    const int bid = blockIdx.x;
    const int xcd = bid & 7;
    const int slot = bid >> 3;            // 0..127
    const int nbit = slot >> 6;           // 0..1
    const int rem = slot & 63;
    const int row = rem & 31;
    const int half = rem >> 5;
    const int n = xcd * 2 + nbit;

    const int c0 = colhalf << 4;
    const int co = (cohalf << 6) + lane;

    const float* sbase = src + ((size_t)n * 128 + half * 64) * 1224;
    const float* wbase = wt + (size_t)half * 64 * 1152 + co;

    const int offA = row * 36 + c0;       // padded row 'row' = x row row-1
    const int offB = offA + 36;
    const int offC = offB + 36;

    float acc[16];
#pragma unroll
    for (int j = 0; j < 16; ++j) acc[j] = 0.f;

    float A[18], B[18], C[18];
    float wa0, wa1, wa2, wb0, wb1, wb2, wc0, wc1, wc2;

    load_rowP(A, sbase + offA);
    load_rowP(B, sbase + offB);
    load_rowP(C, sbase + offC);
    wa0 = wbase[0];   wa1 = wbase[128];  wa2 = wbase[256];
    wb0 = wbase[384]; wb1 = wbase[512];  wb2 = wbase[640];
    wc0 = wbase[768]; wc1 = wbase[896];  wc2 = wbase[1024];

#pragma unroll 1
    for (int p = 0; p < 64; ++p) {
        const int pn = (p + 1 < 64) ? p + 1 : 63;   // clamped prefetch plane
        const float* sp = sbase + pn * 1224;
        const float* wp = wbase + pn * 1152;
        kh_acc(acc, A, wa0, wa1, wa2);
        load_rowP(A, sp + offA);
        wa0 = wp[0];   wa1 = wp[128];  wa2 = wp[256];
        kh_acc(acc, B, wb0, wb1, wb2);
        load_rowP(B, sp + offB);
        wb0 = wp[384]; wb1 = wp[512];  wb2 = wp[640];
        kh_acc(acc, C, wc0, wc1, wc2);
        load_rowP(C, sp + offC);
        wc0 = wp[768]; wc1 = wp[896];  wc2 = wp[1024];
    }

    // Epilogue: coalesced stores, co-fastest partial layout.
    float* dst = half ? dst1 : dst0;
    float* dp = dst + (((size_t)n * 32 + row) * 32 + c0) * 128 + co;
#pragma unroll
    for (int j = 0; j < 16; ++j) dp[j * 128] = acc[j];
}

// ---------------------------------------------------------------------------
// Combine + transpose: partials [n][row][px][co] -> out [n][co][row][px]
// (PADDED=true writes into [n][co][34][36] interior). out = BN(-(pA+pB))
// (+ReLU). Block per (row, n); LDS 32x129 tile.
// ---------------------------------------------------------------------------
template <bool RELU, bool PADDED>
__global__ void combine_bn_t(const float* __restrict__ pA, const float* __restrict__ pB,
                             const float* __restrict__ gamma, const float* __restrict__ beta,
                             const float* __restrict__ mean, const float* __restrict__ var,
                             float* __restrict__ out) {
    const int t = threadIdx.x;
    const int row = blockIdx.x;   // 0..31
    const int n = blockIdx.y;     // 0..15
    __shared__ float tile[32 * 129];
    const size_t base = (((size_t)n * 32 + row) * 32) * 128;  // + px*128 + co

    const int co = t & 127, th = t >> 7;
    const float iv = gamma[co] * rsqrtf(var[co] + BN_EPS);
    const float bb = beta[co] - mean[co] * iv;
#pragma unroll
    for (int e = 0; e < 16; ++e) {
        const int px = e * 2 + th;
        const size_t idx = base + px * 128 + co;
        float z = bb - (pA[idx] + pB[idx]) * iv;
        if (RELU) z = fmaxf(z, 0.f);
        tile[px * 129 + co] = z;
    }
    __syncthreads();
#pragma unroll
    for (int e = 0; e < 4; ++e) {
        const int qidx = e * 256 + t;        // 0..1023 = 128co x 8quads
        const int oco = qidx >> 3, q = qidx & 7;
        float4 v;
        v.x = tile[(4 * q + 0) * 129 + oco];
        v.y = tile[(4 * q + 1) * 129 + oco];
        v.z = tile[(4 * q + 2) * 129 + oco];
        v.w = tile[(4 * q + 3) * 129 + oco];
        if (PADDED) {
            float* op = &out[(((size_t)n * 128 + oco) * 34 + row + 1) * 36 + 1 + 4 * q];
            op[0] = v.x; op[1] = v.y; op[2] = v.z; op[3] = v.w;
        } else {
            *(float4*)&out[(((size_t)n * 128 + oco) * 32 + row) * 32 + 4 * q] = v;
        }
    }
}

// ---------------------------------------------------------------------------
// Per-(n,c) spatial mean of z (standard layout): [16,128,32,32] -> [16,128]
// ---------------------------------------------------------------------------
__global__ void mean_kernel(const float* __restrict__ z, float* __restrict__ means) {
    const int b = blockIdx.x;  // n*128 + c
    const float4 v = ((const float4*)(z + (size_t)b * 1024))[threadIdx.x];
    float sum = v.x + v.y + v.z + v.w;
#pragma unroll
    for (int o = 32; o > 0; o >>= 1) sum += __shfl_down(sum, o);
    __shared__ float ws_[4];
    if ((threadIdx.x & 63) == 0) ws_[threadIdx.x >> 6] = sum;
    __syncthreads();
    if (threadIdx.x == 0)
        means[b] = (ws_[0] + ws_[1] + ws_[2] + ws_[3]) * (1.f / 1024.f);
}

// ---------------------------------------------------------------------------
// SE gate: s = sigmoid(fc2(relu(fc1(mean)+b1))+b2), per image n.
// ---------------------------------------------------------------------------
__global__ void se_kernel(const float* __restrict__ means,
                          const float* __restrict__ fc1w, const float* __restrict__ fc1b,
                          const float* __restrict__ fc2w, const float* __restrict__ fc2b,
                          float* __restrict__ s) {
    const int n = blockIdx.x;     // 16 blocks, 128 threads
    const int t = threadIdx.x;
    __shared__ float m[128], rr[8];
    m[t] = means[n * 128 + t];
    __syncthreads();
    if (t < 8) {
        float a = fc1b[t];
        for (int c2 = 0; c2 < 128; ++c2) a += fc1w[t * 128 + c2] * m[c2];
        rr[t] = fmaxf(a, 0.f);
    }
    __syncthreads();
    float a = fc2b[t];
#pragma unroll
    for (int j = 0; j < 8; ++j) a += fc2w[t * 8 + j] * rr[j];
    s[n * 128 + t] = 1.f / (1.f + expf(-a));
}

// ---------------------------------------------------------------------------
// Final: out = relu(z * s[n,c] + x), vectorized float4 (standard layouts).
// ---------------------------------------------------------------------------
__global__ void final_kernel(const float* __restrict__ z, const float* __restrict__ x,
                             const float* __restrict__ s, float* __restrict__ out) {
    const int i = blockIdx.x * 256 + threadIdx.x;   // float4 index, 524288 total
    const int plane = i >> 8;                        // 256 float4 per (n,c)
    const float sc = s[plane];
    const float4 zv = ((const float4*)z)[i];
    const float4 xv = ((const float4*)x)[i];
    float4 o;
    o.x = fmaxf(zv.x * sc + xv.x, 0.f);
    o.y = fmaxf(zv.y * sc + xv.y, 0.f);
    o.z = fmaxf(zv.z * sc + xv.z, 0.f);
    o.w = fmaxf(zv.w * sc + xv.w, 0.f);
    ((float4*)out)[i] = o;
}

// ---------------------------------------------------------------------------
extern "C" void kernel_launch(void* const* d_in, const int* in_sizes, int n_in,
                              void* d_out, int out_size, void* d_ws, size_t ws_size,
                              hipStream_t stream) {
    const float* x    = (const float*)d_in[0];
    const float* w1   = (const float*)d_in[1];
    const float* g1   = (const float*)d_in[2];
    const float* b1   = (const float*)d_in[3];
    const float* m1   = (const float*)d_in[4];
    const float* v1   = (const float*)d_in[5];
    const float* w2   = (const float*)d_in[6];
    const float* g2   = (const float*)d_in[7];
    const float* b2   = (const float*)d_in[8];
    const float* m2   = (const float*)d_in[9];
    const float* v2   = (const float*)d_in[10];
    const float* fc1w = (const float*)d_in[11];
    const float* fc1b = (const float*)d_in[12];
    const float* fc2w = (const float*)d_in[13];
    const float* fc2b = (const float*)d_in[14];
    float* out = (float*)d_out;

    float* ws    = (float*)d_ws;
    float* wt1   = ws;                   // 147456
    float* wt2   = wt1 + 147456;         // 147456
    float* xp    = wt2 + 147456;         // 2506752 (padded x; later reused as z)
    float* yp    = xp + 2506752;         // 2506752 (padded y)
    float* pA    = yp + 2506752;         // 2097152 (split-0 partial, co-fast)
    float* pB    = pA + 2097152;         // 2097152 (split-1 partial, co-fast)
    float* means = pB + 2097152;         // 2048
    float* s     = means + 2048;         // 2048
    float* z     = xp;                   // xp dead after conv1 -> reuse for z

    wtrans_kernel<<<576, 256, 0, stream>>>(w1, wt1);
    wtrans_kernel<<<576, 256, 0, stream>>>(w2, wt2);
    pad_x_kernel<<<2048, 256, 0, stream>>>(x, xp);
    zero_borders_kernel<<<2048, 256, 0, stream>>>(yp);

    dim3 tgrid(32, 16);
    // Conv1 partials -> pA/pB; combine+transpose -> yp (padded, +ReLU).
    adder_conv_part<<<1024, 256, 0, stream>>>(xp, wt1, pA, pB);
    combine_bn_t<true, true ><<<tgrid, 256, 0, stream>>>(pA, pB, g1, b1, m1, v1, yp);
    // Conv2 partials (src = yp) -> pA/pB; combine+transpose -> z (standard).
    adder_conv_part<<<1024, 256, 0, stream>>>(yp, wt2, pA, pB);
    combine_bn_t<false, false><<<tgrid, 256, 0, stream>>>(pA, pB, g2, b2, m2, v2, z);

    mean_kernel<<<2048, 256, 0, stream>>>(z, means);
    se_kernel<<<16, 128, 0, stream>>>(means, fc1w, fc1b, fc2w, fc2b, s);
    final_kernel<<<2048, 256, 0, stream>>>(z, x, s, out);
}